// Round 4
// baseline (74.823 us; speedup 1.0000x reference)
//
#include <hip/hip_runtime.h>
#include <math.h>

#define BN 256      // batch
#define CN 2048     // channels
#define C4 512      // CN/4
#define EPSF 1e-12f

// ---------------------------------------------------------------------------
// Kernel A: raw Gram D = in @ in^T (256x256, K=2048), fp32, SYMMETRIC.
// Round 4: tile grows 4i -> 8i (8 i-rows x 32 j-cols). Gram is L2-BW-bound
// (per s-iter: 32KB/CU j-loads ~585 cyc vs 256 cyc FMA), and j-row traffic
// = rows/tile x tiles: 8i tiles cut kept blocks 288 -> 144 and L2 traffic
// 83 MB -> 46 MB (~2.4 -> ~1.4 us floor), plus a single dispatch round
// (144 <= 256 CUs; no 2-round tail). Keeps __launch_bounds__(256,1) — round
// 2 proved capping VGPRs hurts; live set here ~350 VGPR (a[8][8]=256 +
// bv[8]=32 + acc/addr) fits the ~500 available at occupancy 1, no spill.
// Grid 256: ib=b>>3 (0..31, 8 i-rows), jb=b&7 (32 j-cols); strict-lower
// tiles (32jb+31 < 8ib) exit early — mirror-covered. Block 64 (exit: ib=8,
// jb=0) zeroes out[0]; kernel boundary orders it before finish.
// BITWISE: per-acc FMA sequence unchanged; 8-way merge-tree reduces lanes in
// the same pairs->quads->octs->... binary-tree order as the 4-way tree ->
// every D[i,j] bit-identical to round 3. jb==7 blocks (ib 0..31) emit
// s_pre[i0..i0+7] from s==7 (j=252+wave) in the same ascending-row add
// order -> bitwise equal si.
// ---------------------------------------------------------------------------
__global__ __launch_bounds__(256, 1) void gram_kernel(const float* __restrict__ in,
                                                      float* __restrict__ D,
                                                      float* __restrict__ s_pre,
                                                      float* __restrict__ out) {
    const int b   = blockIdx.x;
    const int ib  = b >> 3;
    const int jb  = b & 7;
    const int tid = threadIdx.x;

    if (32 * jb + 31 < 8 * ib) {           // strictly-lower tile: mirror-covered
        if (b == 64 && tid == 0) out[0] = 0.f;
        return;
    }

    const int i0   = ib * 8;
    const int j0   = jb * 32;
    const int lane = tid & 63;
    const int wave = tid >> 6;
    const bool odd1 = (lane & 1);
    const bool odd2 = (lane & 2);
    const bool odd4 = (lane & 4);

    __shared__ float s_ctr[32];            // [wave*8 + r]: D[252+wave, i0+r]

    const float4* __restrict__ in4 = (const float4*)in;

    float4 a[8][8];
#pragma unroll
    for (int r = 0; r < 8; ++r)
#pragma unroll
        for (int t = 0; t < 8; ++t)
            a[r][t] = in4[(i0 + r) * C4 + lane + 64 * t];

#pragma unroll 2
    for (int s = 0; s < 8; ++s) {
        const int j = j0 + wave + 4 * s;
        float4 bv[8];
#pragma unroll
        for (int t = 0; t < 8; ++t)
            bv[t] = in4[j * C4 + lane + 64 * t];

        float a0 = 0.f, a1 = 0.f, a2 = 0.f, a3 = 0.f;
        float a4 = 0.f, a5 = 0.f, a6 = 0.f, a7 = 0.f;
#pragma unroll
        for (int t = 0; t < 8; ++t) {
            const float4 b4 = bv[t];
            a0 += a[0][t].x * b4.x + a[0][t].y * b4.y + a[0][t].z * b4.z + a[0][t].w * b4.w;
            a1 += a[1][t].x * b4.x + a[1][t].y * b4.y + a[1][t].z * b4.z + a[1][t].w * b4.w;
            a2 += a[2][t].x * b4.x + a[2][t].y * b4.y + a[2][t].z * b4.z + a[2][t].w * b4.w;
            a3 += a[3][t].x * b4.x + a[3][t].y * b4.y + a[3][t].z * b4.z + a[3][t].w * b4.w;
            a4 += a[4][t].x * b4.x + a[4][t].y * b4.y + a[4][t].z * b4.z + a[4][t].w * b4.w;
            a5 += a[5][t].x * b4.x + a[5][t].y * b4.y + a[5][t].z * b4.z + a[5][t].w * b4.w;
            a6 += a[6][t].x * b4.x + a[6][t].y * b4.y + a[6][t].z * b4.z + a[6][t].w * b4.w;
            a7 += a[7][t].x * b4.x + a[7][t].y * b4.y + a[7][t].z * b4.z + a[7][t].w * b4.w;
        }

        // 8-way merge-tree: lane r in {0..7} ends with acc r reduced over all
        // 64 lanes in the same pairs->quads->octs binary-tree order as before
        const float c01 = (odd1 ? a1 : a0) + __shfl_xor(odd1 ? a0 : a1, 1, 64);
        const float c23 = (odd1 ? a3 : a2) + __shfl_xor(odd1 ? a2 : a3, 1, 64);
        const float c45 = (odd1 ? a5 : a4) + __shfl_xor(odd1 ? a4 : a5, 1, 64);
        const float c67 = (odd1 ? a7 : a6) + __shfl_xor(odd1 ? a6 : a7, 1, 64);
        const float c03 = (odd2 ? c23 : c01) + __shfl_xor(odd2 ? c01 : c23, 2, 64);
        const float c47 = (odd2 ? c67 : c45) + __shfl_xor(odd2 ? c45 : c67, 2, 64);
        float c = (odd4 ? c47 : c03) + __shfl_xor(odd4 ? c03 : c47, 4, 64);
        c += __shfl_xor(c, 8, 64);
        c += __shfl_xor(c, 16, 64);
        c += __shfl_xor(c, 32, 64);

        if (lane < 8) {
            const int i = i0 + lane;
            D[i * BN + j] = c;
            D[j * BN + i] = c;             // mirror (bitwise-identical value)
            if (jb == 7 && s == 7)         // j = 252 + wave: center rows
                s_ctr[wave * 8 + lane] = c;
        }
    }

    if (jb == 7) {                          // block-uniform branch
        __syncthreads();
        if (tid < 8) {
            // ascending center-row add order == old finish si loop -> bitwise
            const float sp = (((s_ctr[tid] + s_ctr[8 + tid]) + s_ctr[16 + tid])
                              + s_ctr[24 + tid]) * 0.25f;
            s_pre[i0 + tid] = sp;
        }
    }
}

// ---------------------------------------------------------------------------
// Kernel B: loss from D. Grid 8 x 256; block handles 32 rows.
// UNCHANGED from round 3 (bitwise-identical output; isolates the gram A/B):
// si precomputed by gram (s_pre); cc from s_s[252..255] in the same
// ascending order; coalesced j4 = q*8+sub main pass; shuffle reductions;
// 8-block atomicAdd into out[0] (zeroed by gram's block 64).
// ---------------------------------------------------------------------------
__global__ __launch_bounds__(256) void finish_kernel(const float* __restrict__ D,
                                                     const float* __restrict__ s_pre,
                                                     const int* __restrict__ targets,
                                                     float* __restrict__ out) {
    const int tid = threadIdx.x;
    const int blk = blockIdx.x;

    __shared__ int   s_t[BN];
    __shared__ float s_s[BN];
    __shared__ float s_inv[BN];
    __shared__ float s_red[4];

    // three independent global loads, issued together
    const int   t_own = targets[tid];
    const float dii   = D[tid * BN + tid];
    const float si    = s_pre[tid];

    s_t[tid] = t_own;
    s_s[tid] = si;
    __syncthreads();

    // cc: same ascending-row add order as the old s_idx loop -> bitwise equal
    const float cc = (((s_s[BN - 4] + s_s[BN - 3]) + s_s[BN - 2]) + s_s[BN - 1]) * 0.25f;

    const float nrm2 = fmaxf(dii - 2.f * si + cc, 0.f);
    const float inv  = 1.0f / fmaxf(sqrtf(nrm2), EPSF);
    s_inv[tid] = inv;
    __syncthreads();

    const int   row  = blk * 32 + (tid >> 3);
    const int   sub  = tid & 7;
    const int   ti   = s_t[row];
    const float siR  = s_s[row];
    const float invR = s_inv[row];

    float pos = INFINITY;
    float neg = 0.f;
    const float4* __restrict__ D4 = (const float4*)D;
#pragma unroll
    for (int q = 0; q < 8; ++q) {
        const int j4 = q * 8 + sub;            // coalesced: 128 B contiguous / 8 lanes
        const float4 d = D4[row * (BN / 4) + j4];
        const int j = 4 * j4;
        const float g0 = (d.x - siR - s_s[j + 0] + cc) * invR * s_inv[j + 0];
        const float g1 = (d.y - siR - s_s[j + 1] + cc) * invR * s_inv[j + 1];
        const float g2 = (d.z - siR - s_s[j + 2] + cc) * invR * s_inv[j + 2];
        const float g3 = (d.w - siR - s_s[j + 3] + cc) * invR * s_inv[j + 3];
        if (s_t[j + 0] == ti) pos = fminf(pos, g0); else neg = fmaxf(neg, fmaxf(g0, 0.f));
        if (s_t[j + 1] == ti) pos = fminf(pos, g1); else neg = fmaxf(neg, fmaxf(g1, 0.f));
        if (s_t[j + 2] == ti) pos = fminf(pos, g2); else neg = fmaxf(neg, fmaxf(g2, 0.f));
        if (s_t[j + 3] == ti) pos = fminf(pos, g3); else neg = fmaxf(neg, fmaxf(g3, 0.f));
    }
    // reduce pos/neg across the 8 sub-threads of this row (contiguous lanes)
#pragma unroll
    for (int off = 1; off <= 4; off <<= 1) {
        pos = fminf(pos, __shfl_xor(pos, off, 64));
        neg = fmaxf(neg, __shfl_xor(neg, off, 64));
    }
    float val = (sub == 0) ? expf(neg - pos) : 0.f;
#pragma unroll
    for (int off = 1; off <= 32; off <<= 1) val += __shfl_xor(val, off, 64);
    if ((tid & 63) == 0) s_red[tid >> 6] = val;
    __syncthreads();
    if (tid == 0)
        atomicAdd(out, (s_red[0] + s_red[1] + s_red[2] + s_red[3]) * (1.0f / 448.0f));
}

extern "C" void kernel_launch(void* const* d_in, const int* in_sizes, int n_in,
                              void* d_out, int out_size, void* d_ws, size_t ws_size,
                              hipStream_t stream) {
    const float* in      = (const float*)d_in[0];
    const int*   targets = (const int*)d_in[1];
    // d_in[2] (subs) is unused by the reference.

    float* D     = (float*)d_ws;             // 256*256 floats = 256 KB
    float* s_pre = D + BN * BN;              // 256 floats
    float* out   = (float*)d_out;

    gram_kernel  <<<256, 256, 0, stream>>>(in, D, s_pre, out);
    finish_kernel<<<8,   256, 0, stream>>>(D, s_pre, targets, out);
}

// Round 5
// 70.756 us; speedup vs baseline: 1.0575x; 1.0575x over previous
//
#include <hip/hip_runtime.h>
#include <math.h>

#define BN 256      // batch
#define CN 2048     // channels
#define C4 512      // CN/4
#define EPSF 1e-12f

// ---------------------------------------------------------------------------
// Kernel A: raw Gram D = in @ in^T (256x256, K=2048), fp32, SYMMETRIC.
// EXACT round-3 known-best (72.1 us). Round-4's 8i tile regressed (+2.7 us):
// 144 blocks pull L2 with only 144 CUs (aggregate L2 BW scales with
// streaming CUs), so halved traffic bought nothing while per-block serial
// work doubled. 4i x 32j / 288 kept blocks / occupancy 1 is the sweet spot:
// 83 MB / 2.4 us = 34.6 TB/s = the measured L2 ceiling. Gram is closed.
// Tiles: ib=b>>3 (4 i-rows), jb=b&7 (32 j-cols); strict-lower tiles exit
// early (mirror-covered). Block 64 (exit) zeroes out[0]. jb==7 blocks emit
// s_pre[i] = (((D[252,i]+D[253,i])+D[254,i])+D[255,i])*0.25 from their s==7
// column (ascending-row add order == original finish si loop -> bitwise).
// ---------------------------------------------------------------------------
__global__ __launch_bounds__(256, 1) void gram_kernel(const float* __restrict__ in,
                                                      float* __restrict__ D,
                                                      float* __restrict__ s_pre,
                                                      float* __restrict__ out) {
    const int b   = blockIdx.x;
    const int ib  = b >> 3;
    const int jb  = b & 7;
    const int tid = threadIdx.x;

    if (32 * jb + 31 < 4 * ib) {           // strictly-lower tile: mirror-covered
        if (b == 64 && tid == 0) out[0] = 0.f;
        return;
    }

    const int i0   = ib * 4;
    const int j0   = jb * 32;
    const int lane = tid & 63;
    const int wave = tid >> 6;
    const bool odd1 = (lane & 1);
    const bool odd2 = (lane & 2);

    __shared__ float s_ctr[16];            // [wave*4 + r]: D[252+wave, i0+r]

    const float4* __restrict__ in4 = (const float4*)in;

    float4 a[4][8];
#pragma unroll
    for (int r = 0; r < 4; ++r)
#pragma unroll
        for (int t = 0; t < 8; ++t)
            a[r][t] = in4[(i0 + r) * C4 + lane + 64 * t];

#pragma unroll 2
    for (int s = 0; s < 8; ++s) {
        const int j = j0 + wave + 4 * s;
        float4 bv[8];
#pragma unroll
        for (int t = 0; t < 8; ++t)
            bv[t] = in4[j * C4 + lane + 64 * t];

        float a0 = 0.f, a1 = 0.f, a2 = 0.f, a3 = 0.f;
#pragma unroll
        for (int t = 0; t < 8; ++t) {
            const float4 b4 = bv[t];
            a0 += a[0][t].x * b4.x + a[0][t].y * b4.y + a[0][t].z * b4.z + a[0][t].w * b4.w;
            a1 += a[1][t].x * b4.x + a[1][t].y * b4.y + a[1][t].z * b4.z + a[1][t].w * b4.w;
            a2 += a[2][t].x * b4.x + a[2][t].y * b4.y + a[2][t].z * b4.z + a[2][t].w * b4.w;
            a3 += a[3][t].x * b4.x + a[3][t].y * b4.y + a[3][t].z * b4.z + a[3][t].w * b4.w;
        }

        // merge-tree reduction: 7 shuffles, lane r in {0..3} ends with acc r
        const float c01 = (odd1 ? a1 : a0) + __shfl_xor(odd1 ? a0 : a1, 1, 64);
        const float c23 = (odd1 ? a3 : a2) + __shfl_xor(odd1 ? a2 : a3, 1, 64);
        float c = (odd2 ? c23 : c01) + __shfl_xor(odd2 ? c01 : c23, 2, 64);
        c += __shfl_xor(c, 4, 64);
        c += __shfl_xor(c, 8, 64);
        c += __shfl_xor(c, 16, 64);
        c += __shfl_xor(c, 32, 64);

        if (lane < 4) {
            const int i = i0 + lane;
            D[i * BN + j] = c;
            D[j * BN + i] = c;             // mirror (bitwise-identical value)
            if (jb == 7 && s == 7)         // j = 252 + wave: center rows
                s_ctr[wave * 4 + lane] = c;
        }
    }

    if (jb == 7) {                          // block-uniform branch
        __syncthreads();
        if (tid < 4) {
            // ascending center-row add order == old finish si loop -> bitwise
            const float sp = (((s_ctr[tid] + s_ctr[4 + tid]) + s_ctr[8 + tid])
                              + s_ctr[12 + tid]) * 0.25f;
            s_pre[i0 + tid] = sp;
        }
    }
}

// ---------------------------------------------------------------------------
// Kernel B: loss from D. Grid 8 x 256; block handles 32 rows.
// Round 5: single-sync preamble + front-loaded latency. All global loads
// (8x float4 D-row, own diag, own s_pre, row's targets/s_pre/diag, the 4
// center s_pre values) issue at kernel entry into one overlapped latency
// window. cc is computed per-thread from s_pre[252..255] directly — same
// ascending add order as before -> bitwise equal. inv is a pure function of
// (dii, si, cc), so each thread computes its own (published via LDS) AND its
// row's invR locally from (diiR, siR, cc) — identical expression, identical
// bits to the old s_inv[row]. One __syncthreads (publish s_t/s_s/s_inv)
// instead of two; main pass and reductions UNCHANGED -> output bitwise
// identical (absmax stays 0.0).
// ---------------------------------------------------------------------------
__global__ __launch_bounds__(256) void finish_kernel(const float* __restrict__ D,
                                                     const float* __restrict__ s_pre,
                                                     const int* __restrict__ targets,
                                                     float* __restrict__ out) {
    const int tid = threadIdx.x;
    const int blk = blockIdx.x;

    __shared__ int   s_t[BN];
    __shared__ float s_s[BN];
    __shared__ float s_inv[BN];
    __shared__ float s_red[4];

    const int row = blk * 32 + (tid >> 3);
    const int sub = tid & 7;

    // ---- all global loads issued up front (one latency window) ----
    const float4* __restrict__ D4 = (const float4*)D;
    float4 drow[8];
#pragma unroll
    for (int q = 0; q < 8; ++q)
        drow[q] = D4[row * (BN / 4) + q * 8 + sub];

    const int   t_own = targets[tid];
    const float dii   = D[tid * BN + tid];
    const float si    = s_pre[tid];
    const int   ti    = targets[row];
    const float diiR  = D[row * BN + row];
    const float siR   = s_pre[row];
    const float sp0   = s_pre[BN - 4];
    const float sp1   = s_pre[BN - 3];
    const float sp2   = s_pre[BN - 2];
    const float sp3   = s_pre[BN - 1];

    // cc: same ascending-row add order as always -> bitwise equal
    const float cc = (((sp0 + sp1) + sp2) + sp3) * 0.25f;

    // own inverse norm (published for the j side)
    const float nrm2 = fmaxf(dii - 2.f * si + cc, 0.f);
    const float inv  = 1.0f / fmaxf(sqrtf(nrm2), EPSF);
    // row inverse norm, computed locally: identical expression on identical
    // inputs -> bitwise identical to the old s_inv[row]
    const float nrm2R = fmaxf(diiR - 2.f * siR + cc, 0.f);
    const float invR  = 1.0f / fmaxf(sqrtf(nrm2R), EPSF);

    s_t[tid]   = t_own;
    s_s[tid]   = si;
    s_inv[tid] = inv;
    __syncthreads();                        // the only barrier

    float pos = INFINITY;
    float neg = 0.f;
#pragma unroll
    for (int q = 0; q < 8; ++q) {
        const float4 d = drow[q];
        const int j = 4 * (q * 8 + sub);
        const float g0 = (d.x - siR - s_s[j + 0] + cc) * invR * s_inv[j + 0];
        const float g1 = (d.y - siR - s_s[j + 1] + cc) * invR * s_inv[j + 1];
        const float g2 = (d.z - siR - s_s[j + 2] + cc) * invR * s_inv[j + 2];
        const float g3 = (d.w - siR - s_s[j + 3] + cc) * invR * s_inv[j + 3];
        if (s_t[j + 0] == ti) pos = fminf(pos, g0); else neg = fmaxf(neg, fmaxf(g0, 0.f));
        if (s_t[j + 1] == ti) pos = fminf(pos, g1); else neg = fmaxf(neg, fmaxf(g1, 0.f));
        if (s_t[j + 2] == ti) pos = fminf(pos, g2); else neg = fmaxf(neg, fmaxf(g2, 0.f));
        if (s_t[j + 3] == ti) pos = fminf(pos, g3); else neg = fmaxf(neg, fmaxf(g3, 0.f));
    }
    // reduce pos/neg across the 8 sub-threads of this row (contiguous lanes)
#pragma unroll
    for (int off = 1; off <= 4; off <<= 1) {
        pos = fminf(pos, __shfl_xor(pos, off, 64));
        neg = fmaxf(neg, __shfl_xor(neg, off, 64));
    }
    float val = (sub == 0) ? expf(neg - pos) : 0.f;
#pragma unroll
    for (int off = 1; off <= 32; off <<= 1) val += __shfl_xor(val, off, 64);
    if ((tid & 63) == 0) s_red[tid >> 6] = val;
    __syncthreads();
    if (tid == 0)
        atomicAdd(out, (s_red[0] + s_red[1] + s_red[2] + s_red[3]) * (1.0f / 448.0f));
}

extern "C" void kernel_launch(void* const* d_in, const int* in_sizes, int n_in,
                              void* d_out, int out_size, void* d_ws, size_t ws_size,
                              hipStream_t stream) {
    const float* in      = (const float*)d_in[0];
    const int*   targets = (const int*)d_in[1];
    // d_in[2] (subs) is unused by the reference.

    float* D     = (float*)d_ws;             // 256*256 floats = 256 KB
    float* s_pre = D + BN * BN;              // 256 floats
    float* out   = (float*)d_out;

    gram_kernel  <<<512, 256, 0, stream>>>(in, D, s_pre, out);
    finish_kernel<<<8,   256, 0, stream>>>(D, s_pre, targets, out);
}